// Round 5
// baseline (439.317 us; speedup 1.0000x reference)
//
#include <hip/hip_runtime.h>

// ---------- types ----------
typedef __attribute__((ext_vector_type(8))) short bf16x8;
typedef __attribute__((ext_vector_type(4))) float f32x4;

#define N_ROWS 3136
#define M_COLS 20000
#define KDIM   1536
#define BM     256
#define BN     256
#define BK     64
#define NT     24             // KDIM / BK
#define NCT2   79             // ceil(20000/256)
#define NRT2   13             // ceil(3136/256)
#define NWG    (NCT2 * NRT2)  // 1027
#define PPR2   (NCT2 * 9)     // 711

// LDS map (160 KB): A triple-buffer 3x32KB @ 0 | B double-buffer 2x32KB @ 98304
#define B_BASE 98304

#define GLOAD_LDS16(g, l) __builtin_amdgcn_global_load_lds( \
    (const __attribute__((address_space(1))) unsigned int*)(g), \
    (__attribute__((address_space(3))) unsigned int*)(l), 16, 0, 0)

__device__ inline unsigned short f2bf(float f) {
    unsigned u = __float_as_uint(f);
    u += 0x7FFFu + ((u >> 16) & 1u);   // RNE
    return (unsigned short)(u >> 16);
}

// sorted ascending insert, drop old max; all indices static after unroll
__device__ inline void t9_insert(float (&t)[9], float v) {
    #pragma unroll
    for (int s = 8; s >= 1; --s)
        t[s] = (v <= t[s-1]) ? t[s-1] : fminf(t[s], v);
    t[0] = fminf(t[0], v);
}

// ---------- fused f32->bf16 conversion + row squared norms (wave per row) ----------
__global__ void cvt_norm_kernel(const float* __restrict__ src,
                                unsigned short* __restrict__ dst,
                                float* __restrict__ norms, int rows) {
    int lane = threadIdx.x & 63;
    int row = blockIdx.x * (blockDim.x >> 6) + (threadIdx.x >> 6);
    if (row >= rows) return;
    const float4* p = (const float4*)(src + (size_t)row * KDIM);
    ushort4* q = (ushort4*)(dst + (size_t)row * KDIM);
    float s = 0.f;
    #pragma unroll
    for (int i = 0; i < 6; ++i) {              // 384 float4 / 64 lanes
        float4 v = p[lane + i * 64];
        s += v.x*v.x + v.y*v.y + v.z*v.z + v.w*v.w;
        ushort4 o;
        o.x = f2bf(v.x); o.y = f2bf(v.y); o.z = f2bf(v.z); o.w = f2bf(v.w);
        q[lane + i * 64] = o;
    }
    #pragma unroll
    for (int off = 32; off > 0; off >>= 1) s += __shfl_down(s, off);
    if (lane == 0) norms[row] = s;
}

// ---------- fused distance GEMM + per-tile top-9 : 256x256 8-phase, deep prefetch ----
// 8 waves (2M x 4N), BK=64. A triple-buffered, B double-buffered (160 KB LDS).
// Tile c stages A(c+2) at q0/q1 and B(c+2) at q2/q3; boundary vmcnt(8) waits only
// on loads issued a FULL K-tile earlier (covers HBM/L3 latency — the R4 stall).
// Swizzle byte ^= ((row&7)<<4); setprio around MFMA clusters.

#define STAGE_A(h, s_, aoff) do { \
    unsigned dstb = (unsigned)(aoff) + ((h) << 14) + ((unsigned)tid << 4); \
    GLOAD_LDS16(gA##h##0 + (size_t)(s_) * BK, smem + dstb); \
    GLOAD_LDS16(gA##h##1 + (size_t)(s_) * BK, smem + dstb + 8192); \
} while (0)
#define STAGE_B(h, s_, boff) do { \
    unsigned dstb = (unsigned)(B_BASE) + (unsigned)(boff) + ((h) << 14) + ((unsigned)tid << 4); \
    GLOAD_LDS16(gB##h##0 + (size_t)(s_) * BK, smem + dstb); \
    GLOAD_LDS16(gB##h##1 + (size_t)(s_) * BK, smem + dstb + 8192); \
} while (0)

#define LDA2(q) \
    a_[0][0] = *(const bf16x8*)(smem + aOff + aBase0 + (2*(q)  )*2048); \
    a_[0][1] = *(const bf16x8*)(smem + aOff + aBase1 + (2*(q)  )*2048); \
    a_[1][0] = *(const bf16x8*)(smem + aOff + aBase0 + (2*(q)+1)*2048); \
    a_[1][1] = *(const bf16x8*)(smem + aOff + aBase1 + (2*(q)+1)*2048);

#define MFMA8(q) \
    _Pragma("unroll") \
    for (int m = 0; m < 2; ++m) { \
        _Pragma("unroll") \
        for (int ni = 0; ni < 4; ++ni) { \
            acc[2*(q)+m][ni] = __builtin_amdgcn_mfma_f32_16x16x32_bf16(a_[m][0], bf[ni][0], acc[2*(q)+m][ni], 0, 0, 0); \
            acc[2*(q)+m][ni] = __builtin_amdgcn_mfma_f32_16x16x32_bf16(a_[m][1], bf[ni][1], acc[2*(q)+m][ni], 0, 0, 0); \
        } \
    }

__global__ __launch_bounds__(512, 2) void dist_topk_kernel(
    const unsigned short* __restrict__ Ag,   // [3136][1536] bf16
    const unsigned short* __restrict__ Bg,   // [20000][1536] bf16
    const float* __restrict__ x2, const float* __restrict__ y2,
    float* __restrict__ partials)
{
    __shared__ __align__(16) unsigned char smem[163840];

    const int tid = threadIdx.x;
    const int wid = tid >> 6, lane = tid & 63;
    const int l15 = lane & 15, l4 = lane >> 4;
    const int wm = wid >> 2, wn = wid & 3;

    // bijective XCD swizzle (m204; 1027 % 8 != 0)
    int orig = blockIdx.x;
    int xcd = orig & 7, li = orig >> 3;
    const int qq = NWG / 8, rr = NWG % 8;   // 128, 3
    int wg = (xcd < rr ? xcd * (qq + 1) : rr * (qq + 1) + (xcd - rr) * qq) + li;
    const int rt = wg / NCT2, ct = wg % NCT2;
    const int rowBase = rt * BM, colBase = ct * BN;

    // ---- staging source pointers: inverse-swizzled global source, linear LDS dest ----
    // swizzle: s = L ^ (((L>>7)&7)<<4)  (involution; bits 4-6 from row bits 0-2)
    auto gsrcA = [&](int h, int j) {
        int L = ((j << 9) + tid) << 4;                  // linear dest byte in 16 KiB half
        int s = L ^ (((L >> 7) & 7) << 4);
        int r = s >> 7, kel = (s & 127) >> 1;
        int grow = rowBase + h * 128 + r; grow = grow < N_ROWS ? grow : N_ROWS - 1;
        return Ag + (size_t)grow * KDIM + kel;
    };
    auto gsrcB = [&](int h, int j) {
        int L = ((j << 9) + tid) << 4;
        int s = L ^ (((L >> 7) & 7) << 4);
        int r = s >> 7, kel = (s & 127) >> 1;
        int gcol = colBase + h * 128 + r; gcol = gcol < M_COLS ? gcol : M_COLS - 1;
        return Bg + (size_t)gcol * KDIM + kel;
    };
    const unsigned short* gA00 = gsrcA(0, 0);
    const unsigned short* gA01 = gsrcA(0, 1);
    const unsigned short* gA10 = gsrcA(1, 0);
    const unsigned short* gA11 = gsrcA(1, 1);
    const unsigned short* gB00 = gsrcB(0, 0);
    const unsigned short* gB01 = gsrcB(0, 1);
    const unsigned short* gB10 = gsrcB(1, 0);
    const unsigned short* gB11 = gsrcB(1, 1);

    // ---- reader fragment LDS base offsets (swizzled). row&7 == l15&7 for all
    // fragments, so swz is mi/ni-invariant; offsets are base + {mi,ni}*2048. ----
    const int swz = (l15 & 7) << 4;
    const int C0 = l4 * 16, C1 = 64 + l4 * 16;
    const int aBase0 = (wm << 14) + l15 * 128 + (C0 ^ swz);
    const int aBase1 = (wm << 14) + l15 * 128 + (C1 ^ swz);
    const int bBase0 = B_BASE + ((wn >> 1) << 14) + ((wn & 1) * 64 + l15) * 128 + (C0 ^ swz);
    const int bBase1 = B_BASE + ((wn >> 1) << 14) + ((wn & 1) * 64 + l15) * 128 + (C1 ^ swz);

    f32x4 acc[8][4] = {};

    // ---- prologue: stage K-tiles 0 and 1 fully (16 loads); wait for tile 0 only ----
    STAGE_A(0, 0, 0);     STAGE_A(1, 0, 0);
    STAGE_B(0, 0, 0);     STAGE_B(1, 0, 0);
    STAGE_A(0, 1, 32768); STAGE_A(1, 1, 32768);
    STAGE_B(0, 1, 32768); STAGE_B(1, 1, 32768);
    asm volatile("s_waitcnt vmcnt(8)" ::: "memory");
    __builtin_amdgcn_s_barrier();

    // ---- main loop: 4 phases per K-tile; stage A(c+2) q0/q1, B(c+2) q2/q3 ----
    int aCur = 0, aStg = 2;                         // c%3 and (c+2)%3
    for (int c = 0; c < NT; ++c) {
        const unsigned aOff  = (unsigned)aCur << 15;
        const unsigned aSOff = (unsigned)aStg << 15;
        const unsigned bOff  = (unsigned)(c & 1) << 15;
        bf16x8 bf[4][2];
        #pragma unroll
        for (int ni = 0; ni < 4; ++ni) {
            bf[ni][0] = *(const bf16x8*)(smem + bOff + bBase0 + ni * 2048);
            bf[ni][1] = *(const bf16x8*)(smem + bOff + bBase1 + ni * 2048);
        }
        bf16x8 a_[2][2];
        // phase 0
        LDA2(0);
        if (c + 2 < NT) STAGE_A(0, c + 2, aSOff);
        __builtin_amdgcn_s_barrier();
        __builtin_amdgcn_s_setprio(1);
        MFMA8(0);
        __builtin_amdgcn_s_setprio(0);
        __builtin_amdgcn_s_barrier();
        // phase 1
        LDA2(1);
        if (c + 2 < NT) STAGE_A(1, c + 2, aSOff);
        __builtin_amdgcn_s_barrier();
        __builtin_amdgcn_s_setprio(1);
        MFMA8(1);
        __builtin_amdgcn_s_setprio(0);
        __builtin_amdgcn_s_barrier();
        // phase 2
        LDA2(2);
        if (c + 2 < NT) STAGE_B(0, c + 2, bOff);
        __builtin_amdgcn_s_barrier();
        __builtin_amdgcn_s_setprio(1);
        MFMA8(2);
        __builtin_amdgcn_s_setprio(0);
        __builtin_amdgcn_s_barrier();
        // phase 3 (+ counted vmcnt at the K-tile boundary)
        LDA2(3);
        if (c + 2 < NT) STAGE_B(1, c + 2, bOff);
        __builtin_amdgcn_s_barrier();
        __builtin_amdgcn_s_setprio(1);
        MFMA8(3);
        __builtin_amdgcn_s_setprio(0);
        if (c < NT - 2)       { asm volatile("s_waitcnt vmcnt(8)" ::: "memory"); }
        else if (c == NT - 2) { asm volatile("s_waitcnt vmcnt(0)" ::: "memory"); }
        __builtin_amdgcn_s_barrier();
        aCur = (aCur == 2) ? 0 : aCur + 1;
        aStg = (aStg == 2) ? 0 : aStg + 1;
    }

    // ---- epilogue: d^2 -> per-row top-9 over this 256-col tile (4 passes of 64 rows)
    // p-loop UNROLLED so every acc index is compile-time (rule #20: no scratch). ----
    float* EpiDs = (float*)smem;                 // [64][265] f32 (odd stride: conflict-free)
    float* EpiT9 = (float*)(smem + 68608);       // [8][64][12] f32
    int ncols = M_COLS - colBase; if (ncols > 256) ncols = 256;

    #pragma unroll
    for (int p = 0; p < 4; ++p) {
        __syncthreads();
        if (wm == (p >> 1)) {
            float xv[4][4];
            #pragma unroll
            for (int ml = 0; ml < 4; ++ml)
                #pragma unroll
                for (int j = 0; j < 4; ++j) {
                    int gr = rowBase + p * 64 + ml * 16 + (l4 << 2) + j;
                    xv[ml][j] = x2[gr < N_ROWS ? gr : N_ROWS - 1];
                }
            #pragma unroll
            for (int ni = 0; ni < 4; ++ni) {
                int cc = wn * 64 + ni * 16 + l15;
                int gc = colBase + cc;
                float yv = y2[gc < M_COLS ? gc : M_COLS - 1];
                #pragma unroll
                for (int ml = 0; ml < 4; ++ml) {
                    #pragma unroll
                    for (int j = 0; j < 4; ++j) {
                        int rloc = ml * 16 + (l4 << 2) + j;
                        EpiDs[rloc * 265 + cc] = xv[ml][j] + yv - 2.0f * acc[((p & 1) << 2) + ml][ni][j];
                    }
                }
            }
        }
        __syncthreads();
        float t9[9];
        #pragma unroll
        for (int s = 0; s < 9; ++s) t9[s] = 3.4e38f;
        {
            int cs = wid * 32, ce = cs + 32 < ncols ? cs + 32 : ncols;
            for (int cc = cs; cc < ce; ++cc)
                t9_insert(t9, EpiDs[lane * 265 + cc]);
        }
        // butterfly over the 8 column-block owners (per row) via LDS
        #pragma unroll
        for (int mm = 4; mm >= 1; mm >>= 1) {
            __syncthreads();
            #pragma unroll
            for (int s = 0; s < 9; ++s) EpiT9[(wid * 64 + lane) * 12 + s] = t9[s];
            __syncthreads();
            #pragma unroll
            for (int s = 0; s < 9; ++s)
                t9_insert(t9, EpiT9[((wid ^ mm) * 64 + lane) * 12 + s]);
        }
        if (wid == 0) {
            int gr = rowBase + p * 64 + lane;
            if (gr < N_ROWS) {
                float* dst = partials + (size_t)gr * PPR2 + ct * 9;
                #pragma unroll
                for (int s = 0; s < 9; ++s) dst[s] = t9[s];
            }
        }
        __syncthreads();
    }
}

// ---------- merge 79 sorted-9 lists per row -> final top-9 (one wave per row) ----------
__global__ void merge_topk_kernel(const float* __restrict__ partials,
                                  float* __restrict__ scores) {
    int lane = threadIdx.x & 63;
    int row = blockIdx.x * 4 + (threadIdx.x >> 6);   // 4 waves/block, 784 blocks
    const float* p = partials + (size_t)row * PPR2;
    float t9[9];
    #pragma unroll
    for (int s = 0; s < 9; ++s) t9[s] = 3.4e38f;
    for (int i = lane; i < PPR2; i += 64) {
        float v = p[i];
        if (v < t9[8]) t9_insert(t9, v);
    }
    #pragma unroll
    for (int off = 32; off > 0; off >>= 1) {
        float o[9];
        #pragma unroll
        for (int s = 0; s < 9; ++s) o[s] = __shfl_xor(t9[s], off);
        #pragma unroll
        for (int s = 0; s < 9; ++s)
            if (o[s] < t9[8]) t9_insert(t9, o[s]);
    }
    if (lane == 0) {
        #pragma unroll
        for (int s = 0; s < 9; ++s)
            scores[row * 9 + s] = sqrtf(fmaxf(t9[s], 0.f));
    }
}

// ---------- gaussian blur (fused with x8 nearest upsample), sigma=4, K=33 ----------
__global__ void blur_h_kernel(const float* __restrict__ scores, float* __restrict__ tH) {
    int idx = blockIdx.x * blockDim.x + threadIdx.x;
    if (idx >= 4 * 224 * 28) return;
    int pw = idx % 28, y = (idx / 28) % 224, b = idx / (28 * 224);
    float acc = 0.f, gsum = 0.f;
    #pragma unroll
    for (int k = 0; k < 33; ++k) {
        float xk = (float)(k - 16);
        float w = expf(-xk * xk * (1.0f / 32.0f));
        gsum += w;
        int yy = y - 16 + k;
        yy = yy < 0 ? -yy : yy;            // reflect
        yy = yy > 223 ? 446 - yy : yy;
        acc += w * scores[(size_t)(b * 784 + (yy >> 3) * 28 + pw) * 9];
    }
    tH[idx] = acc / gsum;
}

__global__ void blur_w_kernel(const float* __restrict__ tH, float* __restrict__ out) {
    int idx = blockIdx.x * blockDim.x + threadIdx.x;
    if (idx >= 4 * 224 * 224) return;
    int x = idx % 224, y = (idx / 224) % 224, b = idx / (224 * 224);
    float acc = 0.f, gsum = 0.f;
    #pragma unroll
    for (int k = 0; k < 33; ++k) {
        float xk = (float)(k - 16);
        float w = expf(-xk * xk * (1.0f / 32.0f));
        gsum += w;
        int xx = x - 16 + k;
        xx = xx < 0 ? -xx : xx;
        xx = xx > 223 ? 446 - xx : xx;
        acc += w * tH[(b * 224 + y) * 28 + (xx >> 3)];
    }
    out[idx] = acc / gsum;
}

// ---------- anomaly score ----------
__global__ void score_kernel(const float* __restrict__ scores, float* __restrict__ out) {
    __shared__ float vmax[256];
    __shared__ int   vidx[256];
    int tid = threadIdx.x;
    float best = -3.4e38f; int bi = 0x7fffffff;
    for (int r = tid; r < N_ROWS; r += 256) {
        float v = scores[r * 9];
        if (v > best) { best = v; bi = r; }
    }
    vmax[tid] = best; vidx[tid] = bi;
    __syncthreads();
    for (int s = 128; s > 0; s >>= 1) {
        if (tid < s) {
            if (vmax[tid + s] > vmax[tid] ||
                (vmax[tid + s] == vmax[tid] && vidx[tid + s] < vidx[tid])) {
                vmax[tid] = vmax[tid + s]; vidx[tid] = vidx[tid + s];
            }
        }
        __syncthreads();
    }
    if (tid == 0) {
        int idx = vidx[0];
        float es = 0.f, em = -3.4e38f;
        #pragma unroll
        for (int s = 0; s < 9; ++s) {
            float e = expf(scores[idx * 9 + s]);
            es += e; em = fmaxf(em, e);
        }
        out[4 * 224 * 224] = (1.0f - em / es) * vmax[0];
    }
}

// ---------- launch ----------
extern "C" void kernel_launch(void* const* d_in, const int* in_sizes, int n_in,
                              void* d_out, int out_size, void* d_ws, size_t ws_size,
                              hipStream_t stream) {
    const float* emb = (const float*)d_in[0];   // [3136,1536]
    const float* mb  = (const float*)d_in[1];   // [20000,1536]
    float* out = (float*)d_out;                 // 200704 amap + 1 score
    char* ws = (char*)d_ws;

    unsigned short* mbb      = (unsigned short*)(ws);             // 61,440,000 B
    unsigned short* embb     = (unsigned short*)(ws + 61440000);  //  9,633,792 B
    float*          x2       = (float*)(ws + 71073792);           //     12,544 B
    float*          y2       = (float*)(ws + 71086336);           //     80,000 B
    float*          partials = (float*)(ws + 71166464);           //  8,918,784 B
    float*          scores   = (float*)(ws + 80085248);           //    112,896 B
    float*          tH       = (float*)(ws + 80198144);           //    100,352 B

    cvt_norm_kernel<<<M_COLS / 4, 256, 0, stream>>>(mb, mbb, y2, M_COLS);
    cvt_norm_kernel<<<N_ROWS / 4, 256, 0, stream>>>(emb, embb, x2, N_ROWS);
    dist_topk_kernel<<<NWG, 512, 0, stream>>>(embb, mbb, x2, y2, partials);
    merge_topk_kernel<<<N_ROWS / 4, 256, 0, stream>>>(partials, scores);
    blur_h_kernel<<<(4 * 224 * 28 + 255) / 256, 256, 0, stream>>>(scores, tH);
    blur_w_kernel<<<(4 * 224 * 224 + 255) / 256, 256, 0, stream>>>(tH, out);
    score_kernel<<<1, 256, 0, stream>>>(scores, out);
}

// Round 6
// 272.909 us; speedup vs baseline: 1.6098x; 1.6098x over previous
//
#include <hip/hip_runtime.h>

// ---------- types ----------
typedef __attribute__((ext_vector_type(4))) int i32x4;

#define N_ROWS 3136
#define M_COLS 20000
#define KDIM   1536
#define NCT    157            // ceil(20000/128)
#define NRT    25             // ceil(3136/128)
#define PPR    (NCT*9)        // 1413

#define QSCL   (4.0f / 127.0f)
#define QINV   (127.0f / 4.0f)
#define TWO_S2 (2.0f * QSCL * QSCL)

#define GLOAD_LDS16(g, l) __builtin_amdgcn_global_load_lds( \
    (const __attribute__((address_space(1))) unsigned int*)(g), \
    (__attribute__((address_space(3))) unsigned int*)(l), 16, 0, 0)

// sorted ascending insert via min/max (2 VALU per slot; rule #20-safe)
__device__ inline void t9_insert(float (&t)[9], float v) {
    #pragma unroll
    for (int s = 8; s >= 1; --s)
        t[s] = fminf(t[s], fmaxf(v, t[s-1]));   // uses OLD t[s-1] (descending order)
    t[0] = fminf(t[0], v);
}

__device__ inline int q8(float x) {
    int q = (int)rintf(x * QINV);
    q = q > 127 ? 127 : q;
    q = q < -127 ? -127 : q;
    return q & 255;
}

// ---------- fused f32->i8 quantization + exact f32 row norms (wave per row) ----------
__global__ void cvt_norm_kernel(const float* __restrict__ src,
                                unsigned char* __restrict__ dst,
                                float* __restrict__ norms, int rows) {
    int lane = threadIdx.x & 63;
    int row = blockIdx.x * (blockDim.x >> 6) + (threadIdx.x >> 6);
    if (row >= rows) return;
    const float4* p = (const float4*)(src + (size_t)row * KDIM);
    int* q = (int*)(dst + (size_t)row * KDIM);
    float s = 0.f;
    #pragma unroll
    for (int i = 0; i < 6; ++i) {              // 384 float4 / 64 lanes
        float4 v = p[lane + i * 64];
        s += v.x*v.x + v.y*v.y + v.z*v.z + v.w*v.w;
        q[lane + i * 64] = q8(v.x) | (q8(v.y) << 8) | (q8(v.z) << 16) | (q8(v.w) << 24);
    }
    #pragma unroll
    for (int off = 32; off > 0; off >>= 1) s += __shfl_down(s, off);
    if (lane == 0) norms[row] = s;
}

// ---------- fused distance GEMM + per-tile top-9 (R2 m97-structure, i8) ----------
// 128x128 tile, K-step 64 (i8), 4 waves (2x2), 16x16x64 i8 MFMA, 4x4 frags/wave.
// Staging via global_load_lds width=16; epilogue LDS overlaid on stage LDS.
union SMem {
    struct { unsigned char As[128 * 64]; unsigned char Bs[128 * 64]; } stage; // 16 KB
    struct { float Ds[64 * 129]; float T9[3 * 64 * 9]; } epi;                 // ~39 KB
};

__global__ __launch_bounds__(256, 4) void dist_topk_kernel(
    const unsigned char* __restrict__ Aq,    // [3136][1536] i8
    const unsigned char* __restrict__ Bq,    // [20000][1536] i8
    const float* __restrict__ x2, const float* __restrict__ y2,
    float* __restrict__ partials)
{
    __shared__ __align__(16) SMem sm;

    const int tid = threadIdx.x;
    const int ct = blockIdx.x, rt = blockIdx.y;
    const int rowBase = rt * 128, colBase = ct * 128;
    const int wave = tid >> 6, lane = tid & 63;

    // staging: 2 x 16B chunks per thread per matrix (128 rows x 64 B)
    const unsigned char* pa[2];
    const unsigned char* pb[2];
    int ldsoff[2];
    #pragma unroll
    for (int i = 0; i < 2; ++i) {
        int flat = i * 256 + tid;        // 0..511
        int r = flat >> 2;               // tile row 0..127
        int kk = (flat & 3) * 16;        // k offset in i8 elements
        int ar = rowBase + r; ar = ar < N_ROWS ? ar : N_ROWS - 1;   // clamp
        int bc = colBase + r; bc = bc < M_COLS ? bc : M_COLS - 1;
        pa[i] = Aq + (size_t)ar * KDIM + kk;
        pb[i] = Bq + (size_t)bc * KDIM + kk;
        ldsoff[i] = flat * 16;           // bytes (lane-linear: legal gload_lds dest)
    }

    const int l15 = lane & 15;
    const int kb = (lane >> 4) * 16;         // fragment k-base (bytes = elements)
    const int g4 = (lane >> 4) * 4;          // C fragment row-base
    const int wr = (wave >> 1) * 64;
    const int wc = (wave & 1) * 64;

    i32x4 acc[4][4] = {};

    for (int kt = 0; kt < 24; ++kt) {
        const int koff = kt * 64;
        #pragma unroll
        for (int i = 0; i < 2; ++i) {
            GLOAD_LDS16(pa[i] + koff, sm.stage.As + ldsoff[i]);
            GLOAD_LDS16(pb[i] + koff, sm.stage.Bs + ldsoff[i]);
        }
        __syncthreads();                     // compiler drains vmcnt(0) before barrier
        i32x4 af[4], bfr[4];
        #pragma unroll
        for (int mi = 0; mi < 4; ++mi)
            af[mi] = *(const i32x4*)(sm.stage.As + (wr + mi * 16 + l15) * 64 + kb);
        #pragma unroll
        for (int ni = 0; ni < 4; ++ni)
            bfr[ni] = *(const i32x4*)(sm.stage.Bs + (wc + ni * 16 + l15) * 64 + kb);
        #pragma unroll
        for (int mi = 0; mi < 4; ++mi)
            #pragma unroll
            for (int ni = 0; ni < 4; ++ni)
                acc[mi][ni] = __builtin_amdgcn_mfma_i32_16x16x64_i8(af[mi], bfr[ni], acc[mi][ni], 0, 0, 0);
        __syncthreads();                     // all reads done before next overwrite
    }

    // epilogue: d^2 = x2 + y2 - 2*s^2*idot -> per-row top-9 (two passes of 64 rows)
    int ncols = M_COLS - colBase; ncols = ncols < 128 ? ncols : 128;

    #pragma unroll
    for (int pass = 0; pass < 2; ++pass) {
        if ((wave >> 1) == pass) {
            #pragma unroll
            for (int ni = 0; ni < 4; ++ni) {
                int c = wc + ni * 16 + l15;
                int gc = colBase + c;
                float yv = y2[gc < M_COLS ? gc : M_COLS - 1];
                #pragma unroll
                for (int mi = 0; mi < 4; ++mi) {
                    #pragma unroll
                    for (int j = 0; j < 4; ++j) {
                        int rloc = mi * 16 + g4 + j;          // 0..63
                        int gr = rowBase + pass * 64 + rloc;
                        float xv = x2[gr < N_ROWS ? gr : N_ROWS - 1];
                        sm.epi.Ds[rloc * 129 + c] = xv + yv - TWO_S2 * (float)acc[mi][ni][j];
                    }
                }
            }
        }
        __syncthreads();
        // 4-way column-split scan: thread (q, r) scans cols [q*32, q*32+32)
        int r = tid & 63, q = tid >> 6;
        int grow = rowBase + pass * 64 + r;
        float t9[9];
        #pragma unroll
        for (int s = 0; s < 9; ++s) t9[s] = 3.4e38f;
        int cs = q * 32;
        int ce = (cs + 32 < ncols) ? cs + 32 : ncols;
        for (int c = cs; c < ce; ++c) t9_insert(t9, sm.epi.Ds[r * 129 + c]);
        if (q > 0) {
            #pragma unroll
            for (int s = 0; s < 9; ++s) sm.epi.T9[((q - 1) * 64 + r) * 9 + s] = t9[s];
        }
        __syncthreads();
        if (q == 0 && grow < N_ROWS) {
            #pragma unroll
            for (int qq = 0; qq < 3; ++qq)
                #pragma unroll
                for (int s = 0; s < 9; ++s)
                    t9_insert(t9, sm.epi.T9[(qq * 64 + r) * 9 + s]);
            float* dst = partials + (size_t)grow * PPR + ct * 9;
            #pragma unroll
            for (int s = 0; s < 9; ++s) dst[s] = t9[s];
        }
        __syncthreads();
    }
}

// ---------- merge 157 sorted-9 lists per row -> final top-9 (one wave per row) ----------
__global__ void merge_topk_kernel(const float* __restrict__ partials,
                                  float* __restrict__ scores) {
    int lane = threadIdx.x & 63;
    int row = blockIdx.x * 4 + (threadIdx.x >> 6);   // 4 waves/block, 784 blocks
    const float* p = partials + (size_t)row * PPR;
    float t9[9];
    #pragma unroll
    for (int s = 0; s < 9; ++s) t9[s] = 3.4e38f;
    for (int i = lane; i < PPR; i += 64) {           // coalesced strided scan
        float v = p[i];
        if (v < t9[8]) t9_insert(t9, v);
    }
    #pragma unroll
    for (int off = 32; off > 0; off >>= 1) {
        float o[9];
        #pragma unroll
        for (int s = 0; s < 9; ++s) o[s] = __shfl_xor(t9[s], off);
        #pragma unroll
        for (int s = 0; s < 9; ++s)
            if (o[s] < t9[8]) t9_insert(t9, o[s]);
    }
    if (lane == 0) {
        #pragma unroll
        for (int s = 0; s < 9; ++s)
            scores[row * 9 + s] = sqrtf(fmaxf(t9[s], 0.f));
    }
}

// ---------- gaussian blur (fused with x8 nearest upsample), sigma=4, K=33 ----------
__global__ void blur_h_kernel(const float* __restrict__ scores, float* __restrict__ tH) {
    int idx = blockIdx.x * blockDim.x + threadIdx.x;
    if (idx >= 4 * 224 * 28) return;
    int pw = idx % 28, y = (idx / 28) % 224, b = idx / (28 * 224);
    float acc = 0.f, gsum = 0.f;
    #pragma unroll
    for (int k = 0; k < 33; ++k) {
        float xk = (float)(k - 16);
        float w = expf(-xk * xk * (1.0f / 32.0f));
        gsum += w;
        int yy = y - 16 + k;
        yy = yy < 0 ? -yy : yy;            // reflect
        yy = yy > 223 ? 446 - yy : yy;
        acc += w * scores[(size_t)(b * 784 + (yy >> 3) * 28 + pw) * 9];
    }
    tH[idx] = acc / gsum;
}

__global__ void blur_w_kernel(const float* __restrict__ tH, float* __restrict__ out) {
    int idx = blockIdx.x * blockDim.x + threadIdx.x;
    if (idx >= 4 * 224 * 224) return;
    int x = idx % 224, y = (idx / 224) % 224, b = idx / (224 * 224);
    float acc = 0.f, gsum = 0.f;
    #pragma unroll
    for (int k = 0; k < 33; ++k) {
        float xk = (float)(k - 16);
        float w = expf(-xk * xk * (1.0f / 32.0f));
        gsum += w;
        int xx = x - 16 + k;
        xx = xx < 0 ? -xx : xx;
        xx = xx > 223 ? 446 - xx : xx;
        acc += w * tH[(b * 224 + y) * 28 + (xx >> 3)];
    }
    out[idx] = acc / gsum;
}

// ---------- anomaly score ----------
__global__ void score_kernel(const float* __restrict__ scores, float* __restrict__ out) {
    __shared__ float vmax[256];
    __shared__ int   vidx[256];
    int tid = threadIdx.x;
    float best = -3.4e38f; int bi = 0x7fffffff;
    for (int r = tid; r < N_ROWS; r += 256) {
        float v = scores[r * 9];
        if (v > best) { best = v; bi = r; }
    }
    vmax[tid] = best; vidx[tid] = bi;
    __syncthreads();
    for (int s = 128; s > 0; s >>= 1) {
        if (tid < s) {
            if (vmax[tid + s] > vmax[tid] ||
                (vmax[tid + s] == vmax[tid] && vidx[tid + s] < vidx[tid])) {
                vmax[tid] = vmax[tid + s]; vidx[tid] = vidx[tid + s];
            }
        }
        __syncthreads();
    }
    if (tid == 0) {
        int idx = vidx[0];
        float es = 0.f, em = -3.4e38f;
        #pragma unroll
        for (int s = 0; s < 9; ++s) {
            float e = expf(scores[idx * 9 + s]);
            es += e; em = fmaxf(em, e);
        }
        out[4 * 224 * 224] = (1.0f - em / es) * vmax[0];
    }
}

// ---------- launch ----------
extern "C" void kernel_launch(void* const* d_in, const int* in_sizes, int n_in,
                              void* d_out, int out_size, void* d_ws, size_t ws_size,
                              hipStream_t stream) {
    const float* emb = (const float*)d_in[0];   // [3136,1536]
    const float* mb  = (const float*)d_in[1];   // [20000,1536]
    float* out = (float*)d_out;                 // 200704 amap + 1 score
    char* ws = (char*)d_ws;

    unsigned char* mbq      = (unsigned char*)(ws);               // 30,720,000 B
    unsigned char* embq     = (unsigned char*)(ws + 30720000);    //  4,816,896 B
    float*         x2       = (float*)(ws + 35536896);            //     12,544 B
    float*         y2       = (float*)(ws + 35549440);            //     80,000 B
    float*         partials = (float*)(ws + 35629440);            // 17,724,672 B
    float*         scores   = (float*)(ws + 53354112);            //    112,896 B
    float*         tH       = (float*)(ws + 53467008);            //    100,352 B

    cvt_norm_kernel<<<M_COLS / 4, 256, 0, stream>>>(mb, mbq, y2, M_COLS);
    cvt_norm_kernel<<<N_ROWS / 4, 256, 0, stream>>>(emb, embq, x2, N_ROWS);
    dist_topk_kernel<<<dim3(NCT, NRT), 256, 0, stream>>>(embq, mbq, x2, y2, partials);
    merge_topk_kernel<<<N_ROWS / 4, 256, 0, stream>>>(partials, scores);
    blur_h_kernel<<<(4 * 224 * 28 + 255) / 256, 256, 0, stream>>>(scores, tH);
    blur_w_kernel<<<(4 * 224 * 224 + 255) / 256, 256, 0, stream>>>(tH, out);
    score_kernel<<<1, 256, 0, stream>>>(scores, out);
}